// Round 10
// baseline (86.017 us; speedup 1.0000x reference)
//
#include <hip/hip_runtime.h>
#include <math.h>

#define NROWS 8192
#define DIM 64
#define KNBR 200
#define NSLICE 8
#define SLICE_ROWS 12500      // 100000 / 8; one slice = 3.2 MB, fits XCD L2
#define BN_EPS 1e-5f
#define BIGF 3.402823466e38f

// ---------- wave-level helpers (wave = 64 lanes) ----------

__device__ __forceinline__ float matvec64(const float* xlds,
                                          const float* __restrict__ W,
                                          int lane) {
    float acc = 0.f;
#pragma unroll
    for (int i4 = 0; i4 < 16; ++i4) {
        float4 xv = *(const float4*)(xlds + i4 * 4);
        acc = fmaf(xv.x, W[(i4 * 4 + 0) * 64 + lane], acc);
        acc = fmaf(xv.y, W[(i4 * 4 + 1) * 64 + lane], acc);
        acc = fmaf(xv.z, W[(i4 * 4 + 2) * 64 + lane], acc);
        acc = fmaf(xv.w, W[(i4 * 4 + 3) * 64 + lane], acc);
    }
    return acc;
}

__device__ __forceinline__ float matvec128(const float* xlds,
                                           const float* __restrict__ W,
                                           int lane) {
    float acc = 0.f;
#pragma unroll
    for (int i4 = 0; i4 < 32; ++i4) {
        float4 xv = *(const float4*)(xlds + i4 * 4);
        acc = fmaf(xv.x, W[(i4 * 4 + 0) * 64 + lane], acc);
        acc = fmaf(xv.y, W[(i4 * 4 + 1) * 64 + lane], acc);
        acc = fmaf(xv.z, W[(i4 * 4 + 2) * 64 + lane], acc);
        acc = fmaf(xv.w, W[(i4 * 4 + 3) * 64 + lane], acc);
    }
    return acc;
}

__device__ __forceinline__ float d2part(const float4 a, const float4 b) {
    const float dx = a.x - b.x, dy = a.y - b.y, dz = a.z - b.z, dw = a.w - b.w;
    float d2 = dx * dx;
    d2 = fmaf(dy, dy, d2);
    d2 = fmaf(dz, dz, d2);
    d2 = fmaf(dw, dw, d2);
    return d2;
}

// ---------- kernel 1: bin each row's neighbors by v_embed slice ----------
// 4 rows per block (one wave each). CSR within the row's 200-entry region:
// ws_list[row*200 + off[s] .. ) holds the idxs of slice s. List order within
// a slice is atomic-arrival order (nondeterministic) but min() over the set
// is order-independent, so the final output is deterministic.
__global__ __launch_bounds__(256) void bin_rows(
    const int* __restrict__ nbr_idx, const int* __restrict__ nbr_len,
    int* __restrict__ ws_list, int* __restrict__ ws_cnt,
    int* __restrict__ ws_off) {
    const int w = threadIdx.x >> 6;
    const int lane = threadIdx.x & 63;
    const int row = blockIdx.x * 4 + w;

    __shared__ int cnt[4][NSLICE];
    __shared__ int off[4][NSLICE];

    if (lane < NSLICE) cnt[w][lane] = 0;
    __syncthreads();

    int len = nbr_len[row];
    if (len < 1) len = 1;
    const int* nb = nbr_idx + (size_t)row * KNBR;

    int myidx[4], myslice[4], mypos[4];
#pragma unroll
    for (int t = 0; t < 4; ++t) {
        const int k = t * 64 + lane;
        const bool v = k < len;
        const int idx = v ? nb[k] : 0;
        const int s = idx / SLICE_ROWS;       // 0..7
        myidx[t] = idx;
        myslice[t] = s;
        mypos[t] = v ? atomicAdd(&cnt[w][s], 1) : 0;
    }
    __syncthreads();
    if (lane == 0) {
        int acc = 0;
#pragma unroll
        for (int s = 0; s < NSLICE; ++s) { off[w][s] = acc; acc += cnt[w][s]; }
    }
    __syncthreads();
#pragma unroll
    for (int t = 0; t < 4; ++t) {
        const int k = t * 64 + lane;
        if (k < len) {
            ws_list[(size_t)row * KNBR + off[w][myslice[t]] + mypos[t]] = myidx[t];
        }
    }
    if (lane < NSLICE) {
        ws_cnt[row * NSLICE + lane] = cnt[w][lane];
        ws_off[row * NSLICE + lane] = off[w][lane];
    }
}

// ---------- kernel 2: heterogeneous main ----------
// blockIdx < 16384: GATHER -- slice s = blockIdx % 8 (matches round-robin
//   block->XCD dispatch, so this block's v_embed slice is L2-resident on its
//   own XCD); 4 rows, one wave each. Quad layout as in R7.
// blockIdx >= 16384: MLP -- 4 rows, one wave each.
#define GATHER_BLOCKS (NROWS / 4 * NSLICE)
__global__ __launch_bounds__(256) void fused_main(
    const float* __restrict__ v_embed,
    const float* __restrict__ u1p, const float* __restrict__ u2p,
    const float* __restrict__ u3p, const float* __restrict__ u4p,
    const float* __restrict__ evp,
    const float* __restrict__ w_ur1, const float* __restrict__ b_ur1,
    const float* __restrict__ w_ur2, const float* __restrict__ b_ur2,
    const float* __restrict__ w_vr1, const float* __restrict__ b_vr1,
    const float* __restrict__ w_vr2, const float* __restrict__ b_vr2,
    const float* __restrict__ w_uv1, const float* __restrict__ b_uv1,
    const float* __restrict__ w_uv2, const float* __restrict__ b_uv2,
    const float* __restrict__ w_uv3, const float* __restrict__ b_uv3,
    const float* __restrict__ bn1_g, const float* __restrict__ bn1_b,
    const float* __restrict__ bn1_m, const float* __restrict__ bn1_v,
    const float* __restrict__ bn2_g, const float* __restrict__ bn2_b,
    const float* __restrict__ bn2_m, const float* __restrict__ bn2_v,
    const float* __restrict__ bn3_g, const float* __restrict__ bn3_b,
    const float* __restrict__ bn3_m, const float* __restrict__ bn3_v,
    const float* __restrict__ bn4_g, const float* __restrict__ bn4_b,
    const float* __restrict__ bn4_m, const float* __restrict__ bn4_v,
    const int* __restrict__ nodes_v, const int* __restrict__ nbr_len,
    const int* __restrict__ ws_list, const int* __restrict__ ws_cnt,
    const int* __restrict__ ws_off,
    float* __restrict__ out_score, float* __restrict__ ws_d2p,
    float* __restrict__ ws_c) {
    const int w = threadIdx.x >> 6;
    const int lane = threadIdx.x & 63;

    __shared__ float xbuf[4][132];

    if (blockIdx.x < GATHER_BLOCKS) {
        // ================= GATHER: (4 rows) x slice s =================
        const int s = blockIdx.x & 7;            // == this block's XCD
        const int row = (blockIdx.x >> 3) * 4 + w;
        const int cnt = ws_cnt[row * NSLICE + s];
        float dmin2 = BIGF;
        if (cnt > 0) {
            const int off = ws_off[row * NSLICE + s];
            const int q16 = lane >> 2;           // neighbor slot in pass (0..15)
            const int sub = lane & 3;            // quad sub-lane
            const int node = nodes_v[row];
            const float4* vrow = (const float4*)(v_embed + ((size_t)node << 6));
            const float4 q0 = vrow[sub + 0];
            const float4 q1 = vrow[sub + 4];
            const float4 q2 = vrow[sub + 8];
            const float4 q3 = vrow[sub + 12];
            const int* lst = ws_list + (size_t)row * KNBR + off;
            const int cm1 = cnt - 1;
            for (int j0 = 0; j0 < cnt; j0 += 16) {
                int j = j0 + q16;
                j = j < cm1 ? j : cm1;           // clamp: duplicate valid, min-safe
                const int idx = lst[j];
                const float4* r = (const float4*)(v_embed + ((size_t)idx << 6));
                const float4 a0 = r[sub + 0];
                const float4 a1 = r[sub + 4];
                const float4 a2 = r[sub + 8];
                const float4 a3 = r[sub + 12];
                float d = d2part(q0, a0) + d2part(q1, a1) + d2part(q2, a2) + d2part(q3, a3);
                d += __shfl_xor(d, 1);
                d += __shfl_xor(d, 2);
                dmin2 = fminf(dmin2, d);
            }
        }
        // wave reduce (quads hold equal values -> start at 4)
        dmin2 = fminf(dmin2, __shfl_xor(dmin2, 4));
        dmin2 = fminf(dmin2, __shfl_xor(dmin2, 8));
        dmin2 = fminf(dmin2, __shfl_xor(dmin2, 16));
        dmin2 = fminf(dmin2, __shfl_xor(dmin2, 32));
        if (lane == 0) ws_d2p[row * NSLICE + s] = dmin2;
        return;
    }

    // ================= MLP block: 4 rows, one wave each =================
    const int row = (blockIdx.x - GATHER_BLOCKS) * 4 + w;
    float* xw = xbuf[w];
    const size_t rb = (size_t)row * DIM + lane;
    const float u1 = u1p[rb], u2 = u2p[rb], u3 = u3p[rb], u4 = u4p[rb];
    const float ev = evp[rb];

    float d12 = u1 - u2, d23 = u2 - u3, d34 = u3 - u4;
    float s1 = d12 * d12, s2 = d23 * d23, s3 = d34 * d34;
#pragma unroll
    for (int m = 1; m < 64; m <<= 1) {
        s1 += __shfl_xor(s1, m);
        s2 += __shfl_xor(s2, m);
        s3 += __shfl_xor(s3, m);
    }
    const float cval = (sqrtf(s1) + sqrtf(s2) + sqrtf(s3)) * (1.0f / 3.0f);

    float eu = u1 * 0.032058603280084993f;
    eu = fmaf(u2, 0.087144318742032567f, eu);
    eu = fmaf(u3, 0.236882818089910134f, eu);
    eu = fmaf(u4, 0.643914259887972245f, eu);

    xw[lane] = eu;
    float t1 = matvec64(xw, w_ur1, lane) + b_ur1[lane];
    t1 = (t1 - bn1_m[lane]) * rsqrtf(bn1_v[lane] + BN_EPS) * bn1_g[lane] + bn1_b[lane];
    t1 = fmaxf(t1, 0.f);
    xw[lane] = t1;
    const float xu = matvec64(xw, w_ur2, lane) + b_ur2[lane];
    xw[lane] = ev;
    float t2 = matvec64(xw, w_vr1, lane) + b_vr1[lane];
    t2 = (t2 - bn2_m[lane]) * rsqrtf(bn2_v[lane] + BN_EPS) * bn2_g[lane] + bn2_b[lane];
    t2 = fmaxf(t2, 0.f);
    xw[lane] = t2;
    const float xv = matvec64(xw, w_vr2, lane) + b_vr2[lane];
    xw[lane] = xu;
    xw[64 + lane] = xv;
    float t3 = matvec128(xw, w_uv1, lane) + b_uv1[lane];
    t3 = (t3 - bn3_m[lane]) * rsqrtf(bn3_v[lane] + BN_EPS) * bn3_g[lane] + bn3_b[lane];
    t3 = fmaxf(t3, 0.f);
    xw[lane] = t3;
    const int jj = lane & 15;
    const int q = lane >> 4;
    float h4 = 0.f;
#pragma unroll
    for (int i = 0; i < 16; ++i) {
        h4 = fmaf(xw[q * 16 + i], w_uv2[(q * 16 + i) * 16 + jj], h4);
    }
    h4 += __shfl_xor(h4, 16);
    h4 += __shfl_xor(h4, 32);
    h4 += b_uv2[jj];
    h4 = (h4 - bn4_m[jj]) * rsqrtf(bn4_v[jj] + BN_EPS) * bn4_g[jj] + bn4_b[jj];
    h4 = fmaxf(h4, 0.f);
    float p = h4 * w_uv3[jj];
#pragma unroll
    for (int m = 1; m < 16; m <<= 1) p += __shfl_xor(p, m);
    const float score = p + b_uv3[0];

    if (lane == 0) {
        out_score[row] = score;
        ws_c[row] = cval;
    }
}

// ---------- final combine: fold slice partials + global min/max + outputs ----------
__global__ __launch_bounds__(1024) void combine(
    const float* __restrict__ ws_d2p, const float* __restrict__ ws_c,
    float* __restrict__ out) {
    const int tid = threadIdx.x;
    __shared__ float red[4][16];

    float ld2[8], lc[8];
    float dmin = BIGF, dmax = -BIGF, cmin = BIGF, cmax = -BIGF;
#pragma unroll
    for (int i = 0; i < 8; ++i) {
        const int b = tid * 8 + i;  // 1024 * 8 == 8192
        float m = ws_d2p[b * NSLICE];
#pragma unroll
        for (int s = 1; s < NSLICE; ++s) m = fminf(m, ws_d2p[b * NSLICE + s]);
        ld2[i] = m;
        lc[i] = ws_c[b];
        dmin = fminf(dmin, m);
        dmax = fmaxf(dmax, m);
        cmin = fminf(cmin, lc[i]);
        cmax = fmaxf(cmax, lc[i]);
    }
#pragma unroll
    for (int m = 1; m < 64; m <<= 1) {
        dmin = fminf(dmin, __shfl_xor(dmin, m));
        dmax = fmaxf(dmax, __shfl_xor(dmax, m));
        cmin = fminf(cmin, __shfl_xor(cmin, m));
        cmax = fmaxf(cmax, __shfl_xor(cmax, m));
    }
    const int wid = tid >> 6;
    const int lane = tid & 63;
    if (lane == 0) {
        red[0][wid] = dmin;
        red[1][wid] = dmax;
        red[2][wid] = cmin;
        red[3][wid] = cmax;
    }
    __syncthreads();
    dmin = red[0][0]; dmax = red[1][0]; cmin = red[2][0]; cmax = red[3][0];
#pragma unroll
    for (int i = 1; i < 16; ++i) {
        dmin = fminf(dmin, red[0][i]);
        dmax = fmaxf(dmax, red[1][i]);
        cmin = fminf(cmin, red[2][i]);
        cmax = fmaxf(cmax, red[3][i]);
    }
    const float dlo = sqrtf(dmin);
    const float dhi = sqrtf(dmax);
    const float inv_d = 1.f / (dhi - dlo);
    const float inv_c = 1.f / (cmax - cmin);
#pragma unroll
    for (int i = 0; i < 8; ++i) {
        const int b = tid * 8 + i;
        const float t = (sqrtf(ld2[i]) - dlo) * inv_d;
        const float unexp = 6.f * t * expf(-6.f * t);
        out[b] += unexp * (lc[i] - cmin) * inv_c;
    }
}

extern "C" void kernel_launch(void* const* d_in, const int* in_sizes, int n_in,
                              void* d_out, int out_size, void* d_ws, size_t ws_size,
                              hipStream_t stream) {
    const float* v_embed = (const float*)d_in[0];
    const float* u1 = (const float*)d_in[1];
    const float* u2 = (const float*)d_in[2];
    const float* u3 = (const float*)d_in[3];
    const float* u4 = (const float*)d_in[4];
    const float* ev = (const float*)d_in[5];
    const float* w_ur1 = (const float*)d_in[6];
    const float* b_ur1 = (const float*)d_in[7];
    const float* w_ur2 = (const float*)d_in[8];
    const float* b_ur2 = (const float*)d_in[9];
    const float* w_vr1 = (const float*)d_in[10];
    const float* b_vr1 = (const float*)d_in[11];
    const float* w_vr2 = (const float*)d_in[12];
    const float* b_vr2 = (const float*)d_in[13];
    const float* w_uv1 = (const float*)d_in[14];
    const float* b_uv1 = (const float*)d_in[15];
    const float* w_uv2 = (const float*)d_in[16];
    const float* b_uv2 = (const float*)d_in[17];
    const float* w_uv3 = (const float*)d_in[18];
    const float* b_uv3 = (const float*)d_in[19];
    const int* nodes_v = (const int*)d_in[20];
    const int* nbr_idx = (const int*)d_in[21];
    const int* nbr_len = (const int*)d_in[22];
    const float* bn1_g = (const float*)d_in[23];
    const float* bn1_b = (const float*)d_in[24];
    const float* bn1_m = (const float*)d_in[25];
    const float* bn1_v = (const float*)d_in[26];
    const float* bn2_g = (const float*)d_in[27];
    const float* bn2_b = (const float*)d_in[28];
    const float* bn2_m = (const float*)d_in[29];
    const float* bn2_v = (const float*)d_in[30];
    const float* bn3_g = (const float*)d_in[31];
    const float* bn3_b = (const float*)d_in[32];
    const float* bn3_m = (const float*)d_in[33];
    const float* bn3_v = (const float*)d_in[34];
    const float* bn4_g = (const float*)d_in[35];
    const float* bn4_b = (const float*)d_in[36];
    const float* bn4_m = (const float*)d_in[37];
    const float* bn4_v = (const float*)d_in[38];

    float* out = (float*)d_out;
    // workspace layout:
    int* ws_list = (int*)d_ws;                         // NROWS*KNBR ints
    int* ws_cnt = ws_list + (size_t)NROWS * KNBR;      // NROWS*8
    int* ws_off = ws_cnt + NROWS * NSLICE;             // NROWS*8
    float* ws_d2p = (float*)(ws_off + NROWS * NSLICE); // NROWS*8
    float* ws_c = ws_d2p + NROWS * NSLICE;             // NROWS

    hipLaunchKernelGGL(bin_rows, dim3(NROWS / 4), dim3(256), 0, stream,
                       nbr_idx, nbr_len, ws_list, ws_cnt, ws_off);
    hipLaunchKernelGGL(fused_main, dim3(GATHER_BLOCKS + NROWS / 4), dim3(256), 0, stream,
                       v_embed, u1, u2, u3, u4, ev,
                       w_ur1, b_ur1, w_ur2, b_ur2, w_vr1, b_vr1, w_vr2, b_vr2,
                       w_uv1, b_uv1, w_uv2, b_uv2, w_uv3, b_uv3,
                       bn1_g, bn1_b, bn1_m, bn1_v,
                       bn2_g, bn2_b, bn2_m, bn2_v,
                       bn3_g, bn3_b, bn3_m, bn3_v,
                       bn4_g, bn4_b, bn4_m, bn4_v,
                       nodes_v, nbr_len, ws_list, ws_cnt, ws_off,
                       out, ws_d2p, ws_c);
    hipLaunchKernelGGL(combine, dim3(1), dim3(1024), 0, stream,
                       ws_d2p, ws_c, out);
}

// Round 11
// 70.221 us; speedup vs baseline: 1.2249x; 1.2249x over previous
//
#include <hip/hip_runtime.h>
#include <math.h>

#define NROWS 8192
#define DIM 64
#define KNBR 200
#define NSLICE 8
#define SLICE_ROWS 12500      // 100000 / 8; one slice = 3.2 MB, fits XCD L2
#define RPB 32                // rows per gather block
#define BN_EPS 1e-5f
#define BIGF 3.402823466e38f

// ---------- wave-level helpers (wave = 64 lanes) ----------

__device__ __forceinline__ float matvec64(const float* xlds,
                                          const float* __restrict__ W,
                                          int lane) {
    float acc = 0.f;
#pragma unroll
    for (int i4 = 0; i4 < 16; ++i4) {
        float4 xv = *(const float4*)(xlds + i4 * 4);
        acc = fmaf(xv.x, W[(i4 * 4 + 0) * 64 + lane], acc);
        acc = fmaf(xv.y, W[(i4 * 4 + 1) * 64 + lane], acc);
        acc = fmaf(xv.z, W[(i4 * 4 + 2) * 64 + lane], acc);
        acc = fmaf(xv.w, W[(i4 * 4 + 3) * 64 + lane], acc);
    }
    return acc;
}

__device__ __forceinline__ float matvec128(const float* xlds,
                                           const float* __restrict__ W,
                                           int lane) {
    float acc = 0.f;
#pragma unroll
    for (int i4 = 0; i4 < 32; ++i4) {
        float4 xv = *(const float4*)(xlds + i4 * 4);
        acc = fmaf(xv.x, W[(i4 * 4 + 0) * 64 + lane], acc);
        acc = fmaf(xv.y, W[(i4 * 4 + 1) * 64 + lane], acc);
        acc = fmaf(xv.z, W[(i4 * 4 + 2) * 64 + lane], acc);
        acc = fmaf(xv.w, W[(i4 * 4 + 3) * 64 + lane], acc);
    }
    return acc;
}

__device__ __forceinline__ float d2part(const float4 a, const float4 b) {
    const float dx = a.x - b.x, dy = a.y - b.y, dz = a.z - b.z, dw = a.w - b.w;
    float d2 = dx * dx;
    d2 = fmaf(dy, dy, d2);
    d2 = fmaf(dz, dz, d2);
    d2 = fmaf(dw, dw, d2);
    return d2;
}

// ---------- kernel 1: bin neighbors by slice + stage dense query rows ----------
// 4 rows per block (one wave each). CSR within the row's 200-entry region.
// List order within a slice is atomic-arrival order (nondeterministic) but
// min() over the set is order-independent -> deterministic output.
// Also copies v_embed[nodes_v[row]] -> ws_q[row] (dense query buffer).
__global__ __launch_bounds__(256) void bin_rows(
    const float* __restrict__ v_embed,
    const int* __restrict__ nodes_v,
    const int* __restrict__ nbr_idx, const int* __restrict__ nbr_len,
    int* __restrict__ ws_list, int* __restrict__ ws_cnt,
    int* __restrict__ ws_off, float* __restrict__ ws_q) {
    const int w = threadIdx.x >> 6;
    const int lane = threadIdx.x & 63;
    const int row = blockIdx.x * 4 + w;

    __shared__ int cnt[4][NSLICE];
    __shared__ int off[4][NSLICE];

    if (lane < NSLICE) cnt[w][lane] = 0;
    __syncthreads();

    // stage query row (dense): 16 lanes x float4
    const int node = nodes_v[row];
    if (lane < 16) {
        const float4 vq = ((const float4*)(v_embed + ((size_t)node << 6)))[lane];
        ((float4*)(ws_q + (size_t)row * DIM))[lane] = vq;
    }

    int len = nbr_len[row];
    if (len < 1) len = 1;
    const int* nb = nbr_idx + (size_t)row * KNBR;

    int myidx[4], myslice[4], mypos[4];
#pragma unroll
    for (int t = 0; t < 4; ++t) {
        const int k = t * 64 + lane;
        const bool v = k < len;
        const int idx = v ? nb[k] : 0;
        const int s = idx / SLICE_ROWS;       // 0..7
        myidx[t] = idx;
        myslice[t] = s;
        mypos[t] = v ? atomicAdd(&cnt[w][s], 1) : 0;
    }
    __syncthreads();
    if (lane == 0) {
        int acc = 0;
#pragma unroll
        for (int s = 0; s < NSLICE; ++s) { off[w][s] = acc; acc += cnt[w][s]; }
    }
    __syncthreads();
#pragma unroll
    for (int t = 0; t < 4; ++t) {
        const int k = t * 64 + lane;
        if (k < len) {
            ws_list[(size_t)row * KNBR + off[w][myslice[t]] + mypos[t]] = myidx[t];
        }
    }
    if (lane < NSLICE) {
        ws_cnt[row * NSLICE + lane] = cnt[w][lane];
        ws_off[row * NSLICE + lane] = off[w][lane];
    }
}

// ---------- kernel 2: heterogeneous main ----------
// blockIdx < GATHER_BLOCKS: GATHER -- slice s = blockIdx % 8 (aligns with
//   round-robin block->XCD dispatch; R10 counters confirmed: FETCH 96->37MB).
//   Block owns 32 rows x 1 slice. Wave w: 8 rows as 2 groups of 4 concurrent
//   rows (16 lanes/row, 4 lanes/neighbor, 4 nbr/pass). cnt/off LDS-staged.
// blockIdx >= GATHER_BLOCKS: MLP -- 4 rows, one wave each.
#define GATHER_BLOCKS (NROWS / RPB * NSLICE)   // 256*8 = 2048
__global__ __launch_bounds__(256) void fused_main(
    const float* __restrict__ v_embed,
    const float* __restrict__ u1p, const float* __restrict__ u2p,
    const float* __restrict__ u3p, const float* __restrict__ u4p,
    const float* __restrict__ evp,
    const float* __restrict__ w_ur1, const float* __restrict__ b_ur1,
    const float* __restrict__ w_ur2, const float* __restrict__ b_ur2,
    const float* __restrict__ w_vr1, const float* __restrict__ b_vr1,
    const float* __restrict__ w_vr2, const float* __restrict__ b_vr2,
    const float* __restrict__ w_uv1, const float* __restrict__ b_uv1,
    const float* __restrict__ w_uv2, const float* __restrict__ b_uv2,
    const float* __restrict__ w_uv3, const float* __restrict__ b_uv3,
    const float* __restrict__ bn1_g, const float* __restrict__ bn1_b,
    const float* __restrict__ bn1_m, const float* __restrict__ bn1_v,
    const float* __restrict__ bn2_g, const float* __restrict__ bn2_b,
    const float* __restrict__ bn2_m, const float* __restrict__ bn2_v,
    const float* __restrict__ bn3_g, const float* __restrict__ bn3_b,
    const float* __restrict__ bn3_m, const float* __restrict__ bn3_v,
    const float* __restrict__ bn4_g, const float* __restrict__ bn4_b,
    const float* __restrict__ bn4_m, const float* __restrict__ bn4_v,
    const int* __restrict__ ws_list, const int* __restrict__ ws_cnt,
    const int* __restrict__ ws_off, const float* __restrict__ ws_q,
    float* __restrict__ out_score, float* __restrict__ ws_d2p,
    float* __restrict__ ws_c) {
    const int w = threadIdx.x >> 6;
    const int lane = threadIdx.x & 63;

    __shared__ float xbuf[4][132];
    __shared__ int scnt[RPB];
    __shared__ int soff[RPB];

    if (blockIdx.x < GATHER_BLOCKS) {
        // ================= GATHER: 32 rows x slice s =================
        const int s = blockIdx.x & 7;            // == this block's XCD
        const int rgroup = blockIdx.x >> 3;
        const int row0 = rgroup * RPB;

        if (threadIdx.x < RPB) {
            scnt[threadIdx.x] = ws_cnt[(row0 + threadIdx.x) * NSLICE + s];
            soff[threadIdx.x] = ws_off[(row0 + threadIdx.x) * NSLICE + s];
        }
        __syncthreads();

        const int riq = lane >> 4;               // row within quad-group (0..3)
        const int slot = (lane >> 2) & 3;        // neighbor slot (0..3)
        const int sub = lane & 3;                // quad sub-lane (0..3)

#pragma unroll
        for (int qg = 0; qg < 2; ++qg) {
            const int lr = w * 8 + qg * 4 + riq; // local row 0..31
            const int row = row0 + lr;
            const int cnt = scnt[lr];
            float dmin2 = BIGF;
            if (cnt > 0) {
                const int off = soff[lr];
                // query from dense buffer (4 loads, coalesced-ish)
                const float4* qr = (const float4*)(ws_q + (size_t)row * DIM);
                const float4 q0 = qr[sub + 0];
                const float4 q1 = qr[sub + 4];
                const float4 q2 = qr[sub + 8];
                const float4 q3 = qr[sub + 12];
                const int* lst = ws_list + (size_t)row * KNBR + off;
                const int cm1 = cnt - 1;
                for (int j0 = 0; j0 < cnt; j0 += 4) {
                    int j = j0 + slot;
                    j = j < cm1 ? j : cm1;       // clamp: duplicate valid, min-safe
                    const int idx = lst[j];
                    const float4* r = (const float4*)(v_embed + ((size_t)idx << 6));
                    const float4 a0 = r[sub + 0];
                    const float4 a1 = r[sub + 4];
                    const float4 a2 = r[sub + 8];
                    const float4 a3 = r[sub + 12];
                    float d = d2part(q0, a0) + d2part(q1, a1)
                            + d2part(q2, a2) + d2part(q3, a3);
                    d += __shfl_xor(d, 1);
                    d += __shfl_xor(d, 2);       // full d^2 on all 4 quad lanes
                    dmin2 = fminf(dmin2, d);
                }
            }
            // min across the 4 neighbor slots of this row's 16-lane group
            dmin2 = fminf(dmin2, __shfl_xor(dmin2, 4));
            dmin2 = fminf(dmin2, __shfl_xor(dmin2, 8));
            if ((lane & 15) == 0) ws_d2p[row * NSLICE + s] = dmin2;
        }
        return;
    }

    // ================= MLP block: 4 rows, one wave each =================
    const int row = (blockIdx.x - GATHER_BLOCKS) * 4 + w;
    float* xw = xbuf[w];
    const size_t rb = (size_t)row * DIM + lane;
    const float u1 = u1p[rb], u2 = u2p[rb], u3 = u3p[rb], u4 = u4p[rb];
    const float ev = evp[rb];

    float d12 = u1 - u2, d23 = u2 - u3, d34 = u3 - u4;
    float s1 = d12 * d12, s2 = d23 * d23, s3 = d34 * d34;
#pragma unroll
    for (int m = 1; m < 64; m <<= 1) {
        s1 += __shfl_xor(s1, m);
        s2 += __shfl_xor(s2, m);
        s3 += __shfl_xor(s3, m);
    }
    const float cval = (sqrtf(s1) + sqrtf(s2) + sqrtf(s3)) * (1.0f / 3.0f);

    float eu = u1 * 0.032058603280084993f;
    eu = fmaf(u2, 0.087144318742032567f, eu);
    eu = fmaf(u3, 0.236882818089910134f, eu);
    eu = fmaf(u4, 0.643914259887972245f, eu);

    xw[lane] = eu;
    float t1 = matvec64(xw, w_ur1, lane) + b_ur1[lane];
    t1 = (t1 - bn1_m[lane]) * rsqrtf(bn1_v[lane] + BN_EPS) * bn1_g[lane] + bn1_b[lane];
    t1 = fmaxf(t1, 0.f);
    xw[lane] = t1;
    const float xu = matvec64(xw, w_ur2, lane) + b_ur2[lane];
    xw[lane] = ev;
    float t2 = matvec64(xw, w_vr1, lane) + b_vr1[lane];
    t2 = (t2 - bn2_m[lane]) * rsqrtf(bn2_v[lane] + BN_EPS) * bn2_g[lane] + bn2_b[lane];
    t2 = fmaxf(t2, 0.f);
    xw[lane] = t2;
    const float xv = matvec64(xw, w_vr2, lane) + b_vr2[lane];
    xw[lane] = xu;
    xw[64 + lane] = xv;
    float t3 = matvec128(xw, w_uv1, lane) + b_uv1[lane];
    t3 = (t3 - bn3_m[lane]) * rsqrtf(bn3_v[lane] + BN_EPS) * bn3_g[lane] + bn3_b[lane];
    t3 = fmaxf(t3, 0.f);
    xw[lane] = t3;
    const int jj = lane & 15;
    const int q = lane >> 4;
    float h4 = 0.f;
#pragma unroll
    for (int i = 0; i < 16; ++i) {
        h4 = fmaf(xw[q * 16 + i], w_uv2[(q * 16 + i) * 16 + jj], h4);
    }
    h4 += __shfl_xor(h4, 16);
    h4 += __shfl_xor(h4, 32);
    h4 += b_uv2[jj];
    h4 = (h4 - bn4_m[jj]) * rsqrtf(bn4_v[jj] + BN_EPS) * bn4_g[jj] + bn4_b[jj];
    h4 = fmaxf(h4, 0.f);
    float p = h4 * w_uv3[jj];
#pragma unroll
    for (int m = 1; m < 16; m <<= 1) p += __shfl_xor(p, m);
    const float score = p + b_uv3[0];

    if (lane == 0) {
        out_score[row] = score;
        ws_c[row] = cval;
    }
}

// ---------- final combine: fold slice partials + global min/max + outputs ----------
__global__ __launch_bounds__(1024) void combine(
    const float* __restrict__ ws_d2p, const float* __restrict__ ws_c,
    float* __restrict__ out) {
    const int tid = threadIdx.x;
    __shared__ float red[4][16];

    float ld2[8], lc[8];
    float dmin = BIGF, dmax = -BIGF, cmin = BIGF, cmax = -BIGF;
#pragma unroll
    for (int i = 0; i < 8; ++i) {
        const int b = tid * 8 + i;  // 1024 * 8 == 8192
        float m = ws_d2p[b * NSLICE];
#pragma unroll
        for (int s = 1; s < NSLICE; ++s) m = fminf(m, ws_d2p[b * NSLICE + s]);
        ld2[i] = m;
        lc[i] = ws_c[b];
        dmin = fminf(dmin, m);
        dmax = fmaxf(dmax, m);
        cmin = fminf(cmin, lc[i]);
        cmax = fmaxf(cmax, lc[i]);
    }
#pragma unroll
    for (int m = 1; m < 64; m <<= 1) {
        dmin = fminf(dmin, __shfl_xor(dmin, m));
        dmax = fmaxf(dmax, __shfl_xor(dmax, m));
        cmin = fminf(cmin, __shfl_xor(cmin, m));
        cmax = fmaxf(cmax, __shfl_xor(cmax, m));
    }
    const int wid = tid >> 6;
    const int lane = tid & 63;
    if (lane == 0) {
        red[0][wid] = dmin;
        red[1][wid] = dmax;
        red[2][wid] = cmin;
        red[3][wid] = cmax;
    }
    __syncthreads();
    dmin = red[0][0]; dmax = red[1][0]; cmin = red[2][0]; cmax = red[3][0];
#pragma unroll
    for (int i = 1; i < 16; ++i) {
        dmin = fminf(dmin, red[0][i]);
        dmax = fmaxf(dmax, red[1][i]);
        cmin = fminf(cmin, red[2][i]);
        cmax = fmaxf(cmax, red[3][i]);
    }
    const float dlo = sqrtf(dmin);
    const float dhi = sqrtf(dmax);
    const float inv_d = 1.f / (dhi - dlo);
    const float inv_c = 1.f / (cmax - cmin);
#pragma unroll
    for (int i = 0; i < 8; ++i) {
        const int b = tid * 8 + i;
        const float t = (sqrtf(ld2[i]) - dlo) * inv_d;
        const float unexp = 6.f * t * expf(-6.f * t);
        out[b] += unexp * (lc[i] - cmin) * inv_c;
    }
}

extern "C" void kernel_launch(void* const* d_in, const int* in_sizes, int n_in,
                              void* d_out, int out_size, void* d_ws, size_t ws_size,
                              hipStream_t stream) {
    const float* v_embed = (const float*)d_in[0];
    const float* u1 = (const float*)d_in[1];
    const float* u2 = (const float*)d_in[2];
    const float* u3 = (const float*)d_in[3];
    const float* u4 = (const float*)d_in[4];
    const float* ev = (const float*)d_in[5];
    const float* w_ur1 = (const float*)d_in[6];
    const float* b_ur1 = (const float*)d_in[7];
    const float* w_ur2 = (const float*)d_in[8];
    const float* b_ur2 = (const float*)d_in[9];
    const float* w_vr1 = (const float*)d_in[10];
    const float* b_vr1 = (const float*)d_in[11];
    const float* w_vr2 = (const float*)d_in[12];
    const float* b_vr2 = (const float*)d_in[13];
    const float* w_uv1 = (const float*)d_in[14];
    const float* b_uv1 = (const float*)d_in[15];
    const float* w_uv2 = (const float*)d_in[16];
    const float* b_uv2 = (const float*)d_in[17];
    const float* w_uv3 = (const float*)d_in[18];
    const float* b_uv3 = (const float*)d_in[19];
    const int* nodes_v = (const int*)d_in[20];
    const int* nbr_idx = (const int*)d_in[21];
    const int* nbr_len = (const int*)d_in[22];
    const float* bn1_g = (const float*)d_in[23];
    const float* bn1_b = (const float*)d_in[24];
    const float* bn1_m = (const float*)d_in[25];
    const float* bn1_v = (const float*)d_in[26];
    const float* bn2_g = (const float*)d_in[27];
    const float* bn2_b = (const float*)d_in[28];
    const float* bn2_m = (const float*)d_in[29];
    const float* bn2_v = (const float*)d_in[30];
    const float* bn3_g = (const float*)d_in[31];
    const float* bn3_b = (const float*)d_in[32];
    const float* bn3_m = (const float*)d_in[33];
    const float* bn3_v = (const float*)d_in[34];
    const float* bn4_g = (const float*)d_in[35];
    const float* bn4_b = (const float*)d_in[36];
    const float* bn4_m = (const float*)d_in[37];
    const float* bn4_v = (const float*)d_in[38];

    float* out = (float*)d_out;
    // workspace layout:
    int* ws_list = (int*)d_ws;                         // NROWS*KNBR ints
    int* ws_cnt = ws_list + (size_t)NROWS * KNBR;      // NROWS*8
    int* ws_off = ws_cnt + NROWS * NSLICE;             // NROWS*8
    float* ws_d2p = (float*)(ws_off + NROWS * NSLICE); // NROWS*8
    float* ws_c = ws_d2p + NROWS * NSLICE;             // NROWS
    float* ws_q = ws_c + NROWS;                        // NROWS*DIM

    hipLaunchKernelGGL(bin_rows, dim3(NROWS / 4), dim3(256), 0, stream,
                       v_embed, nodes_v, nbr_idx, nbr_len,
                       ws_list, ws_cnt, ws_off, ws_q);
    hipLaunchKernelGGL(fused_main, dim3(GATHER_BLOCKS + NROWS / 4), dim3(256), 0, stream,
                       v_embed, u1, u2, u3, u4, ev,
                       w_ur1, b_ur1, w_ur2, b_ur2, w_vr1, b_vr1, w_vr2, b_vr2,
                       w_uv1, b_uv1, w_uv2, b_uv2, w_uv3, b_uv3,
                       bn1_g, bn1_b, bn1_m, bn1_v,
                       bn2_g, bn2_b, bn2_m, bn2_v,
                       bn3_g, bn3_b, bn3_m, bn3_v,
                       bn4_g, bn4_b, bn4_m, bn4_v,
                       ws_list, ws_cnt, ws_off, ws_q,
                       out, ws_d2p, ws_c);
    hipLaunchKernelGGL(combine, dim3(1), dim3(1024), 0, stream,
                       ws_d2p, ws_c, out);
}